// Round 1
// baseline (621.565 us; speedup 1.0000x reference)
//
#include <hip/hip_runtime.h>

namespace {

constexpr int CC = 8;              // channels staged per chunk
constexpr int NRMAX = 5;           // max dy-rows per pass
constexpr int RSTR = 44;           // LDS row stride in floats (40 used + 4 pad)
constexpr int ROWCAP = NRMAX * 9;  // 45 (dy,dx) rows capacity

// One pass over NP displacement pairs [PBASE, PBASE+NP), whose dy values lie
// in [DYLO, DYLO+NR). Thread layout: tid = p*8 + jj; p = pair slot (0..31),
// jj = d-tile (d0 = jj*4). Each thread accumulates 9(k) x 4(d) outputs.
template <int DYLO, int NR, int PBASE, int NP>
__device__ __forceinline__ void do_pass(
    const float* __restrict__ in2b,  // in2 + b*64*32768
    const float* __restrict__ a_lds,
    float* __restrict__ bv_lds,
    float* __restrict__ out,
    int b, int h, int w, int tid)
{
  constexpr int ROWS = NR * 9;
  const int jj = tid & 7;
  const int p = tid >> 3;
  const int d0 = jj * 4;
  const int pair = PBASE + p;
  const bool active = (p < NP);
  const int dy = pair / 9;
  const int dx = pair - dy * 9;
  const int rowidx = active ? (dy - DYLO) * 9 + dx : 0;

  float acc[9][4];
#pragma unroll
  for (int k = 0; k < 9; ++k)
#pragma unroll
    for (int i = 0; i < 4; ++i) acc[k][i] = 0.f;

  for (int cc0 = 0; cc0 < 64; cc0 += CC) {
    __syncthreads();
    // Stage in2 rows: for each (c', dy_r, dx) a 40-float zero-padded row.
    // q indexes float4s within a row: q=0 and q=9 are the pure-zero d-halo
    // (halo is exactly +-4 = one float4), q=1..8 map to d = (q-1)*4 .. +3.
    constexpr int TOTAL4 = CC * ROWS * 10;
    for (int f4 = tid; f4 < TOTAL4; f4 += 256) {
      const int unit = f4 / 10;
      const int q = f4 - unit * 10;
      const int c = unit / ROWS;
      const int r9 = unit - c * ROWS;
      const int dyr = r9 / 9;
      const int dxs = r9 - dyr * 9;
      const int hh = h + DYLO + dyr - 4;
      const int ww = w + dxs - 4;
      float4 v = make_float4(0.f, 0.f, 0.f, 0.f);
      if (q >= 1 && q <= 8 && (unsigned)hh < 32u && (unsigned)ww < 32u) {
        const float* src = in2b + (((size_t)(cc0 + c)) << 15) + (hh << 10) +
                           (ww << 5) + (q * 4 - 4);
        v = *(const float4*)src;
      }
      *(float4*)&bv_lds[(c * ROWCAP + r9) * RSTR + q * 4] = v;
    }
    __syncthreads();
    // Compute: 9 FMAs per LDS float read thanks to k-d reuse window.
#pragma unroll
    for (int c = 0; c < CC; ++c) {
      const float4 a4 = *(const float4*)&a_lds[(cc0 + c) * 32 + d0];
      const float* bvp = &bv_lds[(c * ROWCAP + rowidx) * RSTR + d0];
      float bv[12];
      *(float4*)&bv[0] = *(const float4*)&bvp[0];
      *(float4*)&bv[4] = *(const float4*)&bvp[4];
      *(float4*)&bv[8] = *(const float4*)&bvp[8];
      const float a0 = ((const float*)&a4)[0];
      const float a1 = ((const float*)&a4)[1];
      const float a2 = ((const float*)&a4)[2];
      const float a3 = ((const float*)&a4)[3];
#pragma unroll
      for (int k = 0; k < 9; ++k) {
        acc[k][0] = fmaf(a0, bv[0 + k], acc[k][0]);
        acc[k][1] = fmaf(a1, bv[1 + k], acc[k][1]);
        acc[k][2] = fmaf(a2, bv[2 + k], acc[k][2]);
        acc[k][3] = fmaf(a3, bv[3 + k], acc[k][3]);
      }
    }
  }

  if (active) {
    // out[b, pair*9 + k, h, w, d0..d0+3]
    const size_t obase =
        (((size_t)(b * 729 + pair * 9)) << 15) + (h << 10) + (w << 5) + d0;
#pragma unroll
    for (int k = 0; k < 9; ++k) {
      *(float4*)&out[obase + (((size_t)k) << 15)] =
          make_float4(acc[k][0], acc[k][1], acc[k][2], acc[k][3]);
    }
  }
}

}  // namespace

__global__ __launch_bounds__(256) void corr3d_kernel(
    const float* __restrict__ in1, const float* __restrict__ in2,
    float* __restrict__ out)
{
  __shared__ __align__(16) float a_lds[64 * 32];            // 8 KB
  __shared__ __align__(16) float bv_lds[CC * ROWCAP * RSTR]; // 63360 B
  const int tid = threadIdx.x;
  const int blk = blockIdx.x;
  const int b = blk >> 10;
  const int hw = blk & 1023;
  const int h = hw >> 5;
  const int w = hw & 31;

  // Stage A = in1[b, :, h, w, :] (64 channels x 32 d), float4 coalesced.
  const float* in1b = in1 + (((size_t)b) << 21) + (h << 10) + (w << 5);
  for (int f = tid; f < 512; f += 256) {
    const int c = f >> 3;
    const int dq = f & 7;
    *(float4*)&a_lds[c * 32 + dq * 4] =
        *(const float4*)(in1b + (((size_t)c) << 15) + dq * 4);
  }
  // a_lds readers are separated from these writes by the two barriers inside
  // the first chunk of pass 0.

  const float* in2b = in2 + (((size_t)b) << 21);
  // 81 pairs: dy ranges per pass: [0,3] / [3,7] / [7,8]
  do_pass<0, 4, 0, 32>(in2b, a_lds, bv_lds, out, b, h, w, tid);
  do_pass<3, 5, 32, 32>(in2b, a_lds, bv_lds, out, b, h, w, tid);
  do_pass<7, 2, 64, 17>(in2b, a_lds, bv_lds, out, b, h, w, tid);
}

extern "C" void kernel_launch(void* const* d_in, const int* in_sizes, int n_in,
                              void* d_out, int out_size, void* d_ws, size_t ws_size,
                              hipStream_t stream) {
  const float* in1 = (const float*)d_in[0];
  const float* in2 = (const float*)d_in[1];
  float* out = (float*)d_out;
  // Grid: one block per (b, h, w) = 2*32*32 = 2048 blocks.
  corr3d_kernel<<<dim3(2048), dim3(256), 0, stream>>>(in1, in2, out);
}

// Round 3
// 344.201 us; speedup vs baseline: 1.8058x; 1.8058x over previous
//
#include <hip/hip_runtime.h>

typedef _Float16 half2_t __attribute__((ext_vector_type(2)));

#if defined(__has_builtin)
#if __has_builtin(__builtin_amdgcn_fdot2)
#define HAS_FDOT2 1
#endif
#endif

namespace {

constexpr int BVR = 44;   // bv row stride in half2 units (40 used + 4 pad, 16B-aligned)
constexpr int AR = 36;    // a row stride in half2 units (32 used + 4 pad, 16B-aligned)
constexpr int NROW = 81;  // (dy,dx) rows
constexpr int NU = 2 * NROW * 10;  // staging units per chunk: 2 c-pairs x 81 rows x 10 quads

__device__ __forceinline__ half2_t pkrtz(float a, float b) {
  return __builtin_bit_cast(half2_t, __builtin_amdgcn_cvt_pkrtz(a, b));
}

__device__ __forceinline__ float fdot2(half2_t a, half2_t b, float c) {
#ifdef HAS_FDOT2
  return __builtin_amdgcn_fdot2(a, b, c, false);
#else
  return c + (float)a.x * (float)b.x + (float)a.y * (float)b.y;
#endif
}

}  // namespace

__global__ __launch_bounds__(256, 3) void corr3d_f16(
    const float* __restrict__ in1, const float* __restrict__ in2,
    float* __restrict__ out)
{
  __shared__ __align__(16) half2_t a_lds[32 * AR];          // 4608 B
  __shared__ __align__(16) half2_t bv_lds[2 * NROW * BVR];  // 28512 B

  const int tid = threadIdx.x;
  const int blk = blockIdx.x;
  const int b = blk >> 10;
  const int hw = blk & 1023;
  const int h = hw >> 5;
  const int w = hw & 31;

  const float* in1b = in1 + (((size_t)b) << 21) + (h << 10) + (w << 5);
  const float* in2b = in2 + (((size_t)b) << 21);

  // ---- one-time: zero bv (halo + OOB rows stay zero forever), stage A tile ----
  {
    const float4 z4 = make_float4(0.f, 0.f, 0.f, 0.f);
    float4* bvf4 = (float4*)bv_lds;  // 2*81*44/4 = 1782 float4
    for (int i = tid; i < 1782; i += 256) bvf4[i] = z4;

    // A: in1[b, :, h, w, :] as half2 channel-pairs: a_lds[cpg*AR + d]
    const int ccp = tid >> 3;   // c-pair 0..31
    const int dq = tid & 7;     // d quad
    const float* p0 = in1b + (((size_t)(2 * ccp)) << 15) + dq * 4;
    const float4 va = *(const float4*)p0;
    const float4 vb = *(const float4*)(p0 + 32768);
    half2_t t[4];
    t[0] = pkrtz(va.x, vb.x);
    t[1] = pkrtz(va.y, vb.y);
    t[2] = pkrtz(va.z, vb.z);
    t[3] = pkrtz(va.w, vb.w);
    *(float4*)&a_lds[ccp * AR + dq * 4] = *(float4*)t;
  }

  // ---- loop-invariant staging decode: 7 units/thread ----
  int soff[7], loff[7];
  unsigned valmask = 0;
  {
#pragma unroll
    for (int i = 0; i < 7; ++i) {
      const int u = tid + 256 * i;
      soff[i] = 0;
      loff[i] = 0;
      if (u < NU) {
        const int cp = (u >= 810) ? 1 : 0;
        const int rq = u - cp * 810;
        const int r = rq / 10;        // (dy,dx) row 0..80
        const int q = rq - r * 10;    // d-quad 0..9 (0 and 9 are halo)
        const int dy = r / 9;
        const int dx = r - dy * 9;
        const int hh = h + dy - 4;
        const int ww = w + dx - 4;
        const bool v = (q >= 1) && (q <= 8) && ((unsigned)hh < 32u) && ((unsigned)ww < 32u);
        if (v) {
          valmask |= (1u << i);
          soff[i] = (cp << 16) + (hh << 10) + (ww << 5) + q * 4 - 4;  // even-channel float offset
          loff[i] = (cp * NROW + r) * BVR + q * 4;                    // half2 offset
        }
      }
    }
  }

  // ---- compute thread mapping ----
  const int jj = tid & 7;
  const int p = tid >> 3;
  const int d0 = jj * 4;
  int rowg[3];
#pragma unroll
  for (int g = 0; g < 3; ++g) {
    const int pr = g * 32 + p;
    rowg[g] = pr < NROW ? pr : NROW - 1;  // clamp for inactive lanes (reads only)
  }

  float acc[3][9][4];
#pragma unroll
  for (int g = 0; g < 3; ++g)
#pragma unroll
    for (int k = 0; k < 9; ++k)
#pragma unroll
      for (int i = 0; i < 4; ++i) acc[g][k][i] = 0.f;

  // ---- main loop: 16 chunks of 4 channels (2 c-pairs) ----
  const float* in2c = in2b;
  for (int ch = 0; ch < 16; ++ch) {
    __syncthreads();  // prev compute done / initial zero-fill done
#pragma unroll
    for (int i = 0; i < 7; ++i) {
      if (valmask & (1u << i)) {
        const float* s = in2c + soff[i];
        const float4 va = *(const float4*)s;
        const float4 vb = *(const float4*)(s + 32768);
        half2_t t[4];
        t[0] = pkrtz(va.x, vb.x);
        t[1] = pkrtz(va.y, vb.y);
        t[2] = pkrtz(va.z, vb.z);
        t[3] = pkrtz(va.w, vb.w);
        *(float4*)&bv_lds[loff[i]] = *(float4*)t;
      }
    }
    __syncthreads();

#pragma unroll
    for (int cp = 0; cp < 2; ++cp) {
      const int ccp = (ch << 1) + cp;  // global c-pair
      half2_t a[4];
      *(float4*)a = *(const float4*)&a_lds[ccp * AR + d0];
#pragma unroll
      for (int g = 0; g < 3; ++g) {
        half2_t bv[12];
        const half2_t* bp = &bv_lds[(cp * NROW + rowg[g]) * BVR + d0];
        *(float4*)&bv[0] = *(const float4*)&bp[0];
        *(float4*)&bv[4] = *(const float4*)&bp[4];
        *(float4*)&bv[8] = *(const float4*)&bp[8];
#pragma unroll
        for (int k = 0; k < 9; ++k) {
#pragma unroll
          for (int i = 0; i < 4; ++i)
            acc[g][k][i] = fdot2(a[i], bv[i + k], acc[g][k][i]);
        }
      }
    }
    in2c += 4 << 15;  // advance 4 channels
  }

  // ---- epilogue ----
#pragma unroll
  for (int g = 0; g < 3; ++g) {
    const int pair = g * 32 + p;
    if (pair < NROW) {
      const size_t obase =
          (((size_t)(b * 729 + pair * 9)) << 15) + (h << 10) + (w << 5) + d0;
#pragma unroll
      for (int k = 0; k < 9; ++k) {
        *(float4*)&out[obase + (((size_t)k) << 15)] =
            make_float4(acc[g][k][0], acc[g][k][1], acc[g][k][2], acc[g][k][3]);
      }
    }
  }
}

extern "C" void kernel_launch(void* const* d_in, const int* in_sizes, int n_in,
                              void* d_out, int out_size, void* d_ws, size_t ws_size,
                              hipStream_t stream) {
  const float* in1 = (const float*)d_in[0];
  const float* in2 = (const float*)d_in[1];
  float* out = (float*)d_out;
  corr3d_f16<<<dim3(2048), dim3(256), 0, stream>>>(in1, in2, out);
}

// Round 4
// 294.146 us; speedup vs baseline: 2.1131x; 1.1702x over previous
//
#include <hip/hip_runtime.h>

typedef __fp16 h2 __attribute__((ext_vector_type(2)));
typedef __fp16 h8 __attribute__((ext_vector_type(8)));
typedef float f4 __attribute__((ext_vector_type(4)));

namespace {
constexpr int JSTR = 72;         // halves per j-row (64 c + 8 pad) -> 144 B, breaks bank aliasing
constexpr int JN = 48;           // j rows; j<4 and j>=36 are permanent zero halo
constexpr int COLH = JN * JSTR;  // 3456 halves = 6912 B per column buffer
}

__global__ __launch_bounds__(256, 4) void corr3d_mfma(
    const float* __restrict__ in1, const float* __restrict__ in2,
    float* __restrict__ out)
{
  __shared__ __align__(16) __fp16 colbuf[2][COLH];  // 13824 B, double-buffered in2 column
  __shared__ __align__(16) float obuf[2 * 9 * 32];  // [pos][dz][d] band reorg, 2304 B

  const int tid = threadIdx.x;
  const int blk = blockIdx.x;  // b(2) x h(32) x wb(16)
  const int b = blk >> 9;
  const int h = (blk >> 4) & 31;
  const int w0 = (blk & 15) << 1;  // two w positions: w0, w0+1

  const int lane = tid & 63;
  const int wv = tid >> 6;  // wave 0..3 = D-tiles (T0,s0),(T1,s0),(T1,s1),(T2,s1)
  const int jb = (wv == 0) ? 0 : (wv == 3) ? 32 : 16;  // A-tile j base
  const int db = (wv >= 2) ? 16 : 0;                   // d-strip base
  const int l15 = lane & 15;
  const int lhi = lane >> 4;

  const float* in1b = in1 + ((size_t)b << 21);
  const float* in2b = in2 + ((size_t)b << 21);

  // zero halo rows of both column buffers (j<4, j>=36): written once, never touched again
  for (int i = tid; i < 1152; i += 256) {
    const int bu = i / 576;
    const int r = i - bu * 576;
    const int jrow = r / 36;
    const int cc = r - jrow * 36;
    const int j = (jrow < 4) ? jrow : jrow + 32;
    h2 z = {(__fp16)0.f, (__fp16)0.f};
    *(h2*)&colbuf[bu][j * JSTR + cc * 2] = z;
  }

  // staging role: d = tid&31 (coalesced), c-quad = tid>>5
  const int sd = tid & 31;
  const int scq = tid >> 5;

  auto stage = [&](const float* src, bool valid, __fp16* dst) {
#pragma unroll
    for (int it = 0; it < 4; ++it) {
      const int cp = scq + (it << 3);  // c-pair 0..31
      h2 v = {(__fp16)0.f, (__fp16)0.f};
      if (valid) {
        const float x = src[((size_t)(2 * cp) << 15) + sd];
        const float y = src[((size_t)(2 * cp + 1) << 15) + sd];
        v = __builtin_amdgcn_cvt_pkrtz(x, y);
      }
      *(h2*)&dst[(4 + sd) * JSTR + 2 * cp] = v;  // [j=4+d][c] layout
    }
  };

  // ---- prologue: load in1 B-operand fragments (per wave: its d-strip, 2 c-halves, 2 pos)
  h8 bfr[2][2];
#pragma unroll
  for (int pos = 0; pos < 2; ++pos) {
    __syncthreads();
    stage(in1b + (h << 10) + ((w0 + pos) << 5), true, colbuf[0]);
    __syncthreads();
#pragma unroll
    for (int ch = 0; ch < 2; ++ch)
      bfr[pos][ch] =
          *(const h8*)&colbuf[0][(4 + db + l15) * JSTR + ch * 32 + (lhi << 3)];
  }
  __syncthreads();
  // stage in2 column 0 into buf 0
  {
    const int hp = h - 4, wp = w0 - 4;
    const bool valid = ((unsigned)hp < 32u) && ((unsigned)wp < 32u);
    stage(in2b + (hp << 10) + (wp << 5), valid, colbuf[0]);
  }
  __syncthreads();

  // band-write targets per (lane, reg): m=(lhi*4+r), n=l15; j=jb+m, d=db+n, dz=j-d
  int boff[4];
  unsigned bmask = 0;
#pragma unroll
  for (int r = 0; r < 4; ++r) {
    const int m = (lhi << 2) + r;
    const int dz = jb + m - db - l15;
    if ((unsigned)dz < 9u) bmask |= 1u << r;
    boff[r] = dz * 32 + db + l15;
  }

  // ---- main loop over 90 columns (hc 0..8, wc 0..9)
  for (int ci = 0; ci < 90; ++ci) {
    if (ci + 1 < 90) {  // stage next column into the other buffer
      const int cn = ci + 1;
      const int hcn = cn / 10;
      const int wcn = cn - hcn * 10;
      const int hp = h - 4 + hcn;
      const int wp = w0 - 4 + wcn;
      const bool valid = ((unsigned)hp < 32u) && ((unsigned)wp < 32u);
      stage(in2b + (hp << 10) + (wp << 5), valid, colbuf[cn & 1]);
    }
    const int hc = ci / 10;
    const int wc = ci - hc * 10;
    const bool serve[2] = {wc <= 8, wc >= 1};  // dx = wc - pos must be in [0,9)

    const __fp16* cb = colbuf[ci & 1];
    const h8 a0 = *(const h8*)&cb[(jb + l15) * JSTR + (lhi << 3)];
    const h8 a1 = *(const h8*)&cb[(jb + l15) * JSTR + 32 + (lhi << 3)];
#pragma unroll
    for (int pos = 0; pos < 2; ++pos) {
      if (serve[pos]) {
        f4 acc = {0.f, 0.f, 0.f, 0.f};
        acc = __builtin_amdgcn_mfma_f32_16x16x32_f16(a0, bfr[pos][0], acc, 0, 0, 0);
        acc = __builtin_amdgcn_mfma_f32_16x16x32_f16(a1, bfr[pos][1], acc, 0, 0, 0);
#pragma unroll
        for (int r = 0; r < 4; ++r)
          if (bmask & (1u << r)) obuf[pos * 288 + boff[r]] = acc[r];
      }
    }
    __syncthreads();  // band writes visible
    // readback [pos][dz][d] rows -> coalesced float4 global stores
    if (tid < 144) {
      const int pos = tid >= 72;
      const int rr = tid - pos * 72;
      const int dz = rr >> 3;
      const int q = rr & 7;
      if (serve[pos]) {
        const float4 v = *(const float4*)&obuf[pos * 288 + dz * 32 + (q << 2)];
        const size_t ch = (size_t)(b * 729 + (hc * 9 + (wc - pos)) * 9 + dz);
        *(float4*)(out + (ch << 15) + (h << 10) + ((w0 + pos) << 5) + (q << 2)) = v;
      }
    }
    __syncthreads();  // obuf free for next column's band writes
  }
}

extern "C" void kernel_launch(void* const* d_in, const int* in_sizes, int n_in,
                              void* d_out, int out_size, void* d_ws, size_t ws_size,
                              hipStream_t stream) {
  const float* in1 = (const float*)d_in[0];
  const float* in2 = (const float*)d_in[1];
  float* out = (float*)d_out;
  corr3d_mfma<<<dim3(1024), dim3(256), 0, stream>>>(in1, in2, out);
}